// Round 7
// baseline (231.149 us; speedup 1.0000x reference)
//
#include <hip/hip_runtime.h>

typedef unsigned int uint;
typedef unsigned short ushort;
typedef __attribute__((ext_vector_type(8))) short bf16x8;
typedef __attribute__((ext_vector_type(4))) float f32x4;
typedef __attribute__((ext_vector_type(2))) float f32x2;

#define N_NODES 2000
#define N_EDGES 32000
#define WNUM 2304

// ---------- ws layout (float element offsets) ----------
constexpr size_t OFF_AGG0 = 0;        // 2000*32
constexpr size_t OFF_AGG1 = 64000;    // 2000*48
constexpr size_t OFF_DEN  = 160000;   // 2000*4  (zero-fill covers 0..168000)
constexpr size_t OFF_FLAG = 170000;   // 1 int
constexpr size_t OFF_W2T  = 170004;   // ushort[2][2304][64] = 147456 floats
constexpr size_t OFF_QT0  = 317460;   // 2000*32
constexpr size_t OFF_QT1  = 381460;   // 2000*48
constexpr size_t OFF_W1T  = 509460;   // float[2][64][16] = 2048 floats
constexpr size_t OFF_W1P  = 511508;   // uint[2][64][8]   = 1024 uints (packed bf16 pairs)

__device__ __forceinline__ float b2f(ushort u){ union{uint i; float f;}x; x.i=((uint)u)<<16; return x.f; }
__device__ __forceinline__ float lo16(uint w){ union{uint u; float f;}x; x.u=w<<16; return x.f; }
__device__ __forceinline__ float hi16(uint w){ union{uint u; float f;}x; x.u=w&0xFFFF0000u; return x.f; }
__device__ __forceinline__ ushort f2b(float f){
  union{float f; uint u;}x; x.f=f;
  uint r = (x.u + 0x7FFFu + ((x.u>>16)&1u)) >> 16;
  return (ushort)r;
}
__device__ __forceinline__ float siluf(float x){ return x / (1.f + __expf(-x)); }

template<bool F32>
__device__ __forceinline__ float ldf(const void* p, int i){
  if (F32) return ((const float*)p)[i];
  return b2f(((const ushort*)p)[i]);
}
__device__ __forceinline__ float ldfr(const void* p, int i, bool f32){
  return f32 ? ((const float*)p)[i] : b2f(((const ushort*)p)[i]);
}

// ---------- K0 body: W2 transpose + W1 transpose/pack + node_q + agg zero-fill ----------
template<bool F32>
__device__ void prep_body(
    const void* __restrict__ nf,
    const void* __restrict__ Wk2, const void* __restrict__ Wv2,
    const void* __restrict__ Wk1, const void* __restrict__ Wv1,
    const void* __restrict__ Wq0, const void* __restrict__ Wq1,
    const void* __restrict__ Wd0, const void* __restrict__ Wd1,
    ushort* __restrict__ W2T, float* __restrict__ W1T, uint* __restrict__ W1P,
    float* __restrict__ qt0, float* __restrict__ qt1,
    float* __restrict__ aggz){
  const int t = threadIdx.x;
  const int bid = blockIdx.x;

  if (bid < 72){
    __shared__ ushort tile[64][66];
    const int mat = bid / 36, jt = bid - mat*36;
    const void* W = mat ? Wv2 : Wk2;
    const int j0 = jt*64;
    const int jo = t & 63, cb = t >> 6;
    #pragma unroll
    for (int k=0; k<16; ++k){
      const int c = cb + k*4;
      tile[c][jo] = F32 ? f2b(((const float*)W)[(size_t)c*WNUM + j0 + jo])
                        : ((const ushort*)W)[(size_t)c*WNUM + j0 + jo];
    }
    __syncthreads();
    const int jl = t >> 2, c0 = (t & 3)*16;
    ushort* dst = W2T + (size_t)mat*147456 + (size_t)(j0+jl)*64 + c0;
    #pragma unroll
    for (int k=0; k<16; ++k) dst[k] = tile[c0+k][jl];
  } else if (bid < 104){
    __shared__ float nfL[64][80];
    __shared__ float wq0L[1024], wq1L[256], wd0L[64], wd1L[16];
    const int nb = bid - 72, n0 = nb*64;
    // vectorized staging: nfL region is 64 CONSECUTIVE nf rows (5120 elems linear)
    if (F32){
      for (int idx=t; idx<1280; idx+=256){
        const int gi = n0*20 + idx;            // float4 index, bound 2000*20
        float4 v;
        if (gi < 40000) v = ((const float4*)nf)[gi];
        else { v.x=0.f; v.y=0.f; v.z=0.f; v.w=0.f; }
        ((float4*)&nfL[0][0])[idx] = v;
      }
    } else {
      for (int idx=t; idx<640; idx+=256){
        const int gi = n0*10 + idx;            // uint4(=8 bf16) index, bound 2000*10
        uint4 v;
        if (gi < 20000) v = ((const uint4*)nf)[gi];
        else { v.x=0u; v.y=0u; v.z=0u; v.w=0u; }
        float* d = &nfL[0][0] + idx*8;
        d[0]=lo16(v.x); d[1]=hi16(v.x); d[2]=lo16(v.y); d[3]=hi16(v.y);
        d[4]=lo16(v.z); d[5]=hi16(v.z); d[6]=lo16(v.w); d[7]=hi16(v.w);
      }
    }
    for (int idx=t; idx<1024; idx+=256) wq0L[idx] = ldf<F32>(Wq0, idx);
    if (t < 256) wq1L[t] = ldf<F32>(Wq1, t);
    if (t < 64)  wd0L[t] = ldf<F32>(Wd0, t);
    if (t < 16)  wd1L[t] = ldf<F32>(Wd1, t);
    __syncthreads();
    const int nl = t >> 2, h = t & 3;
    const int nn = n0 + nl;
    if (nn < N_NODES){
      const float* S = &nfL[nl][0];
      float q0[8];
      #pragma unroll
      for (int w=0; w<8; ++w){
        float a = 0.f;
        #pragma unroll
        for (int u=0; u<32; ++u) a += S[u]*wq0L[h*256 + u*8 + w];
        q0[w] = a * 0.17677669529663687f;   // 1/sqrt(32)
      }
      #pragma unroll
      for (int vv=0; vv<8; ++vv){
        float a = 0.f;
        #pragma unroll
        for (int u=0; u<8; ++u) a += q0[u]*wd0L[u*8+vv];
        qt0[nn*32 + h*8 + vv] = a;
      }
      float q1[12];
      #pragma unroll
      for (int w=0; w<4; ++w)
        #pragma unroll
        for (int i=0; i<3; ++i){
          float a = 0.f;
          #pragma unroll
          for (int u=0; u<16; ++u) a += S[32+u*3+i]*wq1L[h*64 + u*4 + w];
          q1[w*3+i] = a * 0.25f;            // 1/sqrt(16)
        }
      #pragma unroll
      for (int vv=0; vv<4; ++vv)
        #pragma unroll
        for (int i=0; i<3; ++i){
          float a = 0.f;
          #pragma unroll
          for (int u=0; u<4; ++u) a += q1[u*3+i]*wd1L[u*4+vv];
          qt1[nn*48 + h*12 + vv*3 + i] = a;
        }
    }
  } else if (bid == 104){
    // W1 transpose (f32) + packed bf16
    for (int idx=t; idx<2048; idx+=256){
      const int mat = idx >> 10, rem = idx & 1023;
      const int c = rem >> 4, b = rem & 15;
      W1T[idx] = ldf<F32>(mat ? Wv1 : Wk1, b*64 + c);
    }
    for (int idx=t; idx<1024; idx+=256){
      const int mat = idx >> 9, rem = idx & 511;
      const int c = rem >> 3, j = rem & 7;
      const void* W = mat ? Wv1 : Wk1;
      ushort u0, u1;
      if (F32){ u0 = f2b(((const float*)W)[(2*j)*64+c]); u1 = f2b(((const float*)W)[(2*j+1)*64+c]); }
      else    { u0 = ((const ushort*)W)[(2*j)*64+c];     u1 = ((const ushort*)W)[(2*j+1)*64+c]; }
      W1P[idx] = (uint)u0 | ((uint)u1 << 16);
    }
  } else {
    // bid 105..120: zero agg0/agg1/denom (168000 floats = 42000 float4), replaces memset launch
    float4 z; z.x=0.f; z.y=0.f; z.z=0.f; z.w=0.f;
    for (int i = (bid-105)*256 + t; i < 42000; i += 4096)
      ((float4*)aggz)[i] = z;
  }
}

__global__ __launch_bounds__(256) void prep_kernel(
    const void* nf,
    const void* Wk2, const void* Wv2,
    const void* Wk1, const void* Wv1,
    const void* Wq0, const void* Wq1,
    const void* Wd0, const void* Wd1,
    ushort* W2T, float* W1T, uint* W1P, float* qt0, float* qt1,
    float* aggz, int* flag){
  __shared__ int s_cnt;
  const int t = threadIdx.x;
  if (t == 0) s_cnt = 0;
  __syncthreads();
  {
    uint u = ((const ushort*)nf)[t*2];
    uint ex = (u >> 7) & 0xFFu;
    if (ex >= 0xA0u) atomicAdd(&s_cnt, 1);
  }
  __syncthreads();
  const bool F32 = (s_cnt >= 20);
  if (blockIdx.x == 0 && t == 0) *flag = F32 ? 1 : 0;
  if (F32) prep_body<true >(nf, Wk2, Wv2, Wk1, Wv1, Wq0, Wq1, Wd0, Wd1, W2T, W1T, W1P, qt0, qt1, aggz);
  else     prep_body<false>(nf, Wk2, Wv2, Wk1, Wv1, Wq0, Wq1, Wd0, Wd1, W2T, W1T, W1P, qt0, qt1, aggz);
}

// ---------- K3: fused edge kernel ----------
// 64 edges/block, 512 threads = 8 waves = (kv:2) x (h:4). Each wave: 36 tiles x 4 Mt.
// Capacity: LDS 77.2KB -> 2 blocks/CU; VGPR must stay <= 128 (4 waves/SIMD) for
// single-residency (500 <= 512). NOTE: plain __launch_bounds__(512) — adding the 2nd
// arg makes hipcc collapse to 64 VGPR and spill (rounds 1 & 5: 67-91 MB scratch).
// Tile loops unrolled x4 to widen the scheduler window (ds_read/L2-prefetch hoisting).
struct Smem {
  ushort hidA[8192];            // [kv][Mt(4)][kh][lane*8] = 16384 B
  union {
    struct {
      float fssT[32][66];       // rows 0..31 (ss*sh0)
      float fvvT[16][66];       // rows 32..47 (seamless continuation)
      float sslT[32][66];
    } f;                        // 21120 B
    float cont[5376];           // [el][h][comp] 64*4*21 (live only after barrier #2)
  } u;                          // 21504 B
  float vshT[3][16][66];        // 12672 B
  float sh1T[3][66];            // 792 B
  float park0[2][4][64][8];     // 16384 B  a0 parked:  [kv][h][el][w<8]
  float parkP[2][4][64][4];     // 8192 B   aP parked:  [kv][h][el][w<4]
  float exL[64][4];             // 1024 B   K->V exp(logit) handoff
  int   dstL[64];               // 256 B
};                              // 77,208 B -> 2 blocks/CU (154 KB <= 160)

__device__ __forceinline__ f32x4 mma_pair(const bf16x8& a0f, const bf16x8& a1f,
                                          bf16x8 b0, bf16x8 b1, float bb){
  f32x4 c = {bb,bb,bb,bb};
  c = __builtin_amdgcn_mfma_f32_16x16x32_bf16(a0f, b0, c, 0,0,0);
  c = __builtin_amdgcn_mfma_f32_16x16x32_bf16(a1f, b1, c, 0,0,0);
  return c;
}
__device__ __forceinline__ void acc_feat(const f32x4 c, const float* fp, float* acc){
  f32x2 fA = *(const f32x2*)(fp);
  f32x2 fB = *(const f32x2*)(fp + 2);
  acc[0] += c[0]*fA[0]; acc[1] += c[1]*fA[1];
  acc[2] += c[2]*fB[0]; acc[3] += c[3]*fB[1];
}

template<bool F32>
__device__ void edge_body(
    const void* __restrict__ nf,  const int* __restrict__ eidx,
    const void* __restrict__ esh, const void* __restrict__ emb,
    const float* __restrict__ W1T, const uint* __restrict__ W1P,
    const void* __restrict__ bk1, const void* __restrict__ bk2,
    const void* __restrict__ bv1, const void* __restrict__ bv2,
    const ushort* __restrict__ W2T,
    const float* __restrict__ qt0g, const float* __restrict__ qt1g,
    float* __restrict__ agg0, float* __restrict__ agg1, float* __restrict__ denom,
    Smem& sm){
  const int t  = threadIdx.x;
  const int geb = blockIdx.x*64;

  // ---- Phase A: 16 groups x 4 edges, batched gathers (sequential edge ids) ----
  {
    const int g = t >> 5, r = t & 31;
    int geA[4], srcA[4], dstA[4];
    float shv0[4], shv1[4], shv2[4], shv3[4];
    #pragma unroll
    for (int e=0; e<4; ++e) geA[e] = geb + g*4 + e;
    #pragma unroll
    for (int e=0; e<4; ++e){ srcA[e] = eidx[geA[e]]; dstA[e] = eidx[N_EDGES + geA[e]]; }
    #pragma unroll
    for (int e=0; e<4; ++e){
      if (F32){
        float4 s4 = ((const float4*)esh)[geA[e]];
        shv0[e]=s4.x; shv1[e]=s4.y; shv2[e]=s4.z; shv3[e]=s4.w;
      } else {
        uint2 u2 = ((const uint2*)esh)[geA[e]];
        shv0[e]=lo16(u2.x); shv1[e]=hi16(u2.x); shv2[e]=lo16(u2.y); shv3[e]=hi16(u2.y);
      }
    }
    #pragma unroll
    for (int e=0; e<4; ++e){
      const int le = g*4+e, src = srcA[e];
      const float sh0 = shv0[e], s1a = shv1[e], s1b = shv2[e], s1c = shv3[e];
      if (r == 0) sm.dstL[le] = dstA[e];
      if (r < 3) sm.sh1T[r][le] = (r==0)? s1a : (r==1)? s1b : s1c;
      float sv = ldf<F32>(nf, src*80 + r);
      sm.u.f.sslT[r][le] = sv;
      sm.u.f.fssT[r][le] = sv * sh0;
      if (r < 16){
        float v0 = ldf<F32>(nf, src*80+32+r*3+0);
        float v1 = ldf<F32>(nf, src*80+32+r*3+1);
        float v2 = ldf<F32>(nf, src*80+32+r*3+2);
        sm.vshT[0][r][le] = v0*sh0; sm.vshT[1][r][le] = v1*sh0; sm.vshT[2][r][le] = v2*sh0;
        sm.u.f.fvvT[r][le] = (v0*s1a + v1*s1b + v2*s1c) * 0.5773502691896258f;
      }
    }
  }

  // ---- Phase B: radial MLP hidden; 1 column x 8 edges per thread ----
  {
    const int c  = t & 63;
    const int g8 = t >> 6;
    const int le0 = g8*8;
    float bkv = ldf<F32>(bk1, c), bvv = ldf<F32>(bv1, c);
    f32x4 wkF[4], wvF[4];       // F32 instantiation only
    uint4 wkB[2], wvB[2];       // bf16 instantiation only
    if (F32){
      const f32x4* pk = (const f32x4*)(W1T + c*16);
      const f32x4* pv = (const f32x4*)(W1T + 1024 + c*16);
      wkF[0]=pk[0]; wkF[1]=pk[1]; wkF[2]=pk[2]; wkF[3]=pk[3];
      wvF[0]=pv[0]; wvF[1]=pv[1]; wvF[2]=pv[2]; wvF[3]=pv[3];
    } else {
      const uint4* pk = (const uint4*)(W1P + c*8);
      const uint4* pv = (const uint4*)(W1P + 512 + c*8);
      wkB[0]=pk[0]; wkB[1]=pk[1];
      wvB[0]=pv[0]; wvB[1]=pv[1];
    }
    uint4 ra, rb; float4 fa, fb, fc, fd;
    if (F32){
      const float4* p = (const float4*)emb + (size_t)(geb+le0)*4;
      fa = p[0]; fb = p[1]; fc = p[2]; fd = p[3];
    } else {
      const uint4* p = (const uint4*)emb + (size_t)(geb+le0)*2;
      ra = p[0]; rb = p[1];
    }
    #pragma unroll
    for (int e=0; e<8; ++e){
      float em[16];
      if (F32){
        em[0]=fa.x; em[1]=fa.y; em[2]=fa.z; em[3]=fa.w;
        em[4]=fb.x; em[5]=fb.y; em[6]=fb.z; em[7]=fb.w;
        em[8]=fc.x; em[9]=fc.y; em[10]=fc.z; em[11]=fc.w;
        em[12]=fd.x; em[13]=fd.y; em[14]=fd.z; em[15]=fd.w;
      } else {
        em[0]=lo16(ra.x); em[1]=hi16(ra.x); em[2]=lo16(ra.y); em[3]=hi16(ra.y);
        em[4]=lo16(ra.z); em[5]=hi16(ra.z); em[6]=lo16(ra.w); em[7]=hi16(ra.w);
        em[8]=lo16(rb.x); em[9]=hi16(rb.x); em[10]=lo16(rb.y); em[11]=hi16(rb.y);
        em[12]=lo16(rb.z); em[13]=hi16(rb.z); em[14]=lo16(rb.w); em[15]=hi16(rb.w);
      }
      if (e < 7){
        if (F32){
          const float4* p = (const float4*)emb + (size_t)(geb+le0+e+1)*4;
          fa = p[0]; fb = p[1]; fc = p[2]; fd = p[3];
        } else {
          const uint4* p = (const uint4*)emb + (size_t)(geb+le0+e+1)*2;
          ra = p[0]; rb = p[1];
        }
      }
      const int le = le0+e;
      float ak = bkv, av = bvv;
      if (F32){
        #pragma unroll
        for (int g=0; g<4; ++g)
          #pragma unroll
          for (int j=0; j<4; ++j){
            ak += em[g*4+j]*wkF[g][j];
            av += em[g*4+j]*wvF[g][j];
          }
      } else {
        #pragma unroll
        for (int g=0; g<2; ++g){
          const uint4 a = wkB[g], b = wvB[g];
          ak += em[g*8+0]*lo16(a.x) + em[g*8+1]*hi16(a.x)
              + em[g*8+2]*lo16(a.y) + em[g*8+3]*hi16(a.y)
              + em[g*8+4]*lo16(a.z) + em[g*8+5]*hi16(a.z)
              + em[g*8+6]*lo16(a.w) + em[g*8+7]*hi16(a.w);
          av += em[g*8+0]*lo16(b.x) + em[g*8+1]*hi16(b.x)
              + em[g*8+2]*lo16(b.y) + em[g*8+3]*hi16(b.y)
              + em[g*8+4]*lo16(b.z) + em[g*8+5]*hi16(b.z)
              + em[g*8+6]*lo16(b.w) + em[g*8+7]*hi16(b.w);
        }
      }
      // fragment-linear hidA index: Mt*1024 + kh*512 + (q*16+m)*8 + j   (kv offset 0/4096)
      const int idx = (le>>4)*1024 + (c>>5)*512 + ((((c>>3)&3)*16 + (le&15))<<3) + (c&7);
      sm.hidA[idx]        = f2b(siluf(ak));
      sm.hidA[4096 + idx] = f2b(siluf(av));
    }
  }
  __syncthreads();   // barrier #1: hidA + features ready

  // ---- Phase C: one 36-tile pass per wave; wave = (kv, h); 4 Mt per step ----
  const int w  = t >> 6;
  const int kv = w >> 2;
  const int h  = w & 3;
  const int lane = t & 63, q = lane >> 4, n = lane & 15;
  const float invfan = 0.14433756729740643f;   // 1/sqrt(48)

  const ushort* wptr = W2T + (size_t)kv*147456 + h*36864 + n*64 + q*8;  // tile stride 1024
  const void* bvec = kv ? bv2 : bk2;
  const int bi0 = h*576 + n;                        // bias idx, tile stride 16
  const float* fb_ss = &sm.u.f.fssT[n>>3][q*4];     // + tl*132 + Mt*16 (rows 0..47 seamless)
  const float* fb_sl = &sm.u.f.sslT[n>>2][q*4];     // + (tl-24)*264 + Mt*16
  const int nq2 = n>>2;

  bf16x8 af[4][2];
  #pragma unroll
  for (int Mt=0; Mt<4; ++Mt)
    #pragma unroll
    for (int kh=0; kh<2; ++kh)
      af[Mt][kh] = *(const bf16x8*)&sm.hidA[kv*4096 + Mt*1024 + kh*512 + lane*8];

#define PREF(P0,P1,PB,TL) \
  P0 = *(const bf16x8*)(wptr + (TL)*1024); \
  P1 = *(const bf16x8*)(wptr + (TL)*1024 + 32); \
  PB = ldf<F32>(bvec, bi0 + (TL)*16);

  // 2-deep ping-pong prefetch
  bf16x8 pA0, pA1, pB0, pB1; float pAb, pBb;
  PREF(pA0, pA1, pAb, 0);
  PREF(pB0, pB1, pBb, 1);

  // ss tiles 0..15 + vv tiles 16..23 -> a0
  {
    float a0[4][4];
    #pragma unroll
    for (int Mt=0; Mt<4; ++Mt){ a0[Mt][0]=0.f; a0[Mt][1]=0.f; a0[Mt][2]=0.f; a0[Mt][3]=0.f; }
    #pragma unroll 4
    for (int tl=0; tl<24; tl+=2){
      { bf16x8 b0=pA0, b1=pA1; float bb=pAb;
        PREF(pA0, pA1, pAb, tl+2);
        const float* fp = fb_ss + tl*132;
        #pragma unroll
        for (int Mt=0; Mt<4; ++Mt) acc_feat(mma_pair(af[Mt][0], af[Mt][1], b0, b1, bb), fp + Mt*16, a0[Mt]); }
      { bf16x8 b0=pB0, b1=pB1; float bb=pBb;
        PREF(pB0, pB1, pBb, tl+3);
        const float* fp = fb_ss + (tl+1)*132;
        #pragma unroll
        for (int Mt=0; Mt<4; ++Mt) acc_feat(mma_pair(af[Mt][0], af[Mt][1], b0, b1, bb), fp + Mt*16, a0[Mt]); }
    }
    // reduce + park a0 (freed before aP phase)
    #pragma unroll
    for (int Mt=0; Mt<4; ++Mt)
      #pragma unroll
      for (int z=0; z<4; ++z){
        a0[Mt][z] += __shfl_xor(a0[Mt][z], 8, 64);
        if (n < 8) sm.park0[kv][h][Mt*16 + q*4 + z][n] = a0[Mt][z];
      }
  }

  // sv tiles 24..31 -> aP
  {
    float aP[4][4];
    #pragma unroll
    for (int Mt=0; Mt<4; ++Mt){ aP[Mt][0]=0.f; aP[Mt][1]=0.f; aP[Mt][2]=0.f; aP[Mt][3]=0.f; }
    #pragma unroll
    for (int tl=24; tl<32; tl+=2){
      { bf16x8 b0=pA0, b1=pA1; float bb=pAb;
        PREF(pA0, pA1, pAb, tl+2);
        const float* fp = fb_sl + (tl-24)*264;
        #pragma unroll
        for (int Mt=0; Mt<4; ++Mt) acc_feat(mma_pair(af[Mt][0], af[Mt][1], b0, b1, bb), fp + Mt*16, aP[Mt]); }
      { bf16x8 b0=pB0, b1=pB1; float bb=pBb;
        PREF(pB0, pB1, pBb, tl+3);
        const float* fp = fb_sl + (tl-23)*264;
        #pragma unroll
        for (int Mt=0; Mt<4; ++Mt) acc_feat(mma_pair(af[Mt][0], af[Mt][1], b0, b1, bb), fp + Mt*16, aP[Mt]); }
    }
    // reduce + park aP
    #pragma unroll
    for (int Mt=0; Mt<4; ++Mt)
      #pragma unroll
      for (int z=0; z<4; ++z){
        aP[Mt][z] += __shfl_xor(aP[Mt][z], 4, 64);
        aP[Mt][z] += __shfl_xor(aP[Mt][z], 8, 64);
        if (n < 4) sm.parkP[kv][h][Mt*16 + q*4 + z][n] = aP[Mt][z];
      }
  }

  // vs tiles 32..35 -> aW[i] (kept in registers)
  float aW[3][4][4];
  #pragma unroll
  for (int i=0; i<3; ++i)
    #pragma unroll
    for (int Mt=0; Mt<4; ++Mt){ aW[i][Mt][0]=0.f; aW[i][Mt][1]=0.f; aW[i][Mt][2]=0.f; aW[i][Mt][3]=0.f; }
#define BODY_AW(B0,B1,BB,TL) { \
    const int u = ((TL)-32)*4 + nq2; \
    _Pragma("unroll") \
    for (int Mt=0; Mt<4; ++Mt){ \
      f32x4 c = mma_pair(af[Mt][0], af[Mt][1], B0, B1, BB); \
      _Pragma("unroll") \
      for (int i=0; i<3; ++i) acc_feat(c, &sm.vshT[i][u][Mt*16+q*4], aW[i][Mt]); \
    } }
  { bf16x8 b0=pA0, b1=pA1; float bb=pAb; PREF(pA0, pA1, pAb, 34); BODY_AW(b0,b1,bb,32); }
  { bf16x8 b0=pB0, b1=pB1; float bb=pBb; PREF(pB0, pB1, pBb, 35); BODY_AW(b0,b1,bb,33); }
  { bf16x8 b0=pA0, b1=pA1; float bb=pAb; BODY_AW(b0,b1,bb,34); }
  { bf16x8 b0=pB0, b1=pB1; float bb=pBb; BODY_AW(b0,b1,bb,35); }
#undef BODY_AW
#undef PREF
  #pragma unroll
  for (int i=0; i<3; ++i)
    #pragma unroll
    for (int Mt=0; Mt<4; ++Mt)
      #pragma unroll
      for (int z=0; z<4; ++z){
        aW[i][Mt][z] += __shfl_xor(aW[i][Mt][z], 4, 64);
        aW[i][Mt][z] += __shfl_xor(aW[i][Mt][z], 8, 64);
      }

  if (kv == 0){
    // K-waves: logits -> exp -> exL handoff
    float lgp[4][4];
    #pragma unroll
    for (int Mt=0; Mt<4; ++Mt)
      #pragma unroll
      for (int z=0; z<4; ++z){
        const int el = Mt*16 + q*4 + z;
        const int d = sm.dstL[el];
        float acc = 0.f;
        if (n < 8) acc = qt0g[d*32 + h*8 + n] * sm.park0[0][h][el][n];
        if (n < 4){
          const float aPv = sm.parkP[0][h][el][n];
          float s = 0.f;
          #pragma unroll
          for (int i=0; i<3; ++i){
            float k1 = aPv*sm.sh1T[i][el] + aW[i][Mt][z];
            s += qt1g[d*48 + h*12 + n*3 + i] * k1;
          }
          acc += s * 0.5773502691896258f;
        }
        lgp[Mt][z] = acc;
      }
    #pragma unroll
    for (int Mt=0; Mt<4; ++Mt)
      #pragma unroll
      for (int z=0; z<4; ++z){
        lgp[Mt][z] += __shfl_xor(lgp[Mt][z], 1, 64);
        lgp[Mt][z] += __shfl_xor(lgp[Mt][z], 2, 64);
        lgp[Mt][z] += __shfl_xor(lgp[Mt][z], 4, 64);
        lgp[Mt][z] += __shfl_xor(lgp[Mt][z], 8, 64);
      }
    if (n == 0){
      #pragma unroll
      for (int Mt=0; Mt<4; ++Mt)
        #pragma unroll
        for (int z=0; z<4; ++z){
          float lg = lgp[Mt][z] * invfan * 0.025f;   // 1/(sqrt(80)*sqrt(20))
          lg = fminf(10.f, fmaxf(-10.f, lg));
          sm.exL[Mt*16 + q*4 + z][h] = __expf(lg - 10.0f);  // fixed softmax max = 10
        }
    }
  }
  __syncthreads();   // barrier #2: exL ready; all tile-loop feature reads done

  if (kv == 1){
    // V-waves: stage cont (overlays feature arrays — protected by barrier #2)
    #pragma unroll
    for (int Mt=0; Mt<4; ++Mt)
      #pragma unroll
      for (int z=0; z<4; ++z){
        const int el = Mt*16 + q*4 + z;
        const float ex = sm.exL[el][h];
        float* cp = &sm.u.cont[el*84 + h*21];
        if (n == 0) cp[0] = ex;
        if (n < 8)  cp[1+n] = ex * sm.park0[1][h][el][n] * invfan;
        if (n < 4){
          const float aPv = sm.parkP[1][h][el][n];
          #pragma unroll
          for (int i=0; i<3; ++i){
            float v1 = (aPv*sm.sh1T[i][el] + aW[i][Mt][z]) * invfan;
            cp[9+n*3+i] = ex * v1;
          }
        }
      }
  }
  __syncthreads();   // barrier #3: cont ready

  // flat atomic scatter: 5376 values, stride-1 LDS reads (conflict-free)
  #pragma unroll
  for (int k=0; k<11; ++k){
    const int idx = t + k*512;
    if (idx < 5376){
      const int el = idx / 84;
      const int cm = idx - el*84;
      const int h2 = cm / 21;
      const int comp = cm - h2*21;
      const float val = sm.u.cont[idx];
      const int d2 = sm.dstL[el];
      if (comp == 0)      atomicAdd(denom + d2*4  + h2, val);
      else if (comp < 9)  atomicAdd(agg0  + d2*32 + h2*8  + (comp-1), val);
      else                atomicAdd(agg1  + d2*48 + h2*12 + (comp-9), val);
    }
  }
}

__global__ __launch_bounds__(512) void edge_kernel(
    const void* nf, const int* eidx, const void* esh, const void* emb,
    const float* W1T, const uint* W1P,
    const void* bk1, const void* bk2,
    const void* bv1, const void* bv2,
    const ushort* W2T, const float* qt0g, const float* qt1g,
    float* agg0, float* agg1, float* denom, const int* flag){
  __shared__ Smem sm;
  if (*flag)
    edge_body<true >(nf,eidx,esh,emb,W1T,W1P,bk1,bk2,bv1,bv2,W2T,qt0g,qt1g,agg0,agg1,denom,sm);
  else
    edge_body<false>(nf,eidx,esh,emb,W1T,W1P,bk1,bk2,bv1,bv2,W2T,qt0g,qt1g,agg0,agg1,denom,sm);
}

// ---------- K4: per-node output MLP (4 nodes per 256-thread block) ----------
__global__ __launch_bounds__(256) void node_out_kernel(
    const void* __restrict__ nf, const float* __restrict__ agg0r, const float* __restrict__ agg1r,
    const float* __restrict__ denom,
    const void* __restrict__ Wo0, const void* __restrict__ Wo1,
    const void* __restrict__ Wf10, const void* __restrict__ Wf11,
    const void* __restrict__ Wf20, const void* __restrict__ Wf21,
    void* __restrict__ out, const int* __restrict__ flag){
  __shared__ float ag0[4][32], ag1[4][48], adiv[4][4];
  __shared__ float x0s[4][32], x1s[4][48], a0s[4][64], f1s[4][48], coefs[4][16];
  const bool F32 = (*flag) != 0;
  const int s = threadIdx.x >> 6, t = threadIdx.x & 63;
  const int n = blockIdx.x*4 + s;
  if (t < 4) adiv[s][t] = 1.f / (denom[n*4+t] + 1e-12f);
  __syncthreads();
  if (t < 32) ag0[s][t] = agg0r[n*32+t] * adiv[s][t>>3];
  if (t < 48) ag1[s][t] = agg1r[n*48+t] * adiv[s][t/12];
  __syncthreads();
  if (t < 32){
    float o = 0.f;
    #pragma unroll
    for (int k=0; k<32; ++k) o += ag0[s][k]*ldfr(Wo0, k*32+t, F32);
    x0s[s][t] = ldfr(nf, n*80+t, F32) + o*0.17677669529663687f;
  }
  if (t < 48){
    int w = t/3, i = t - w*3;
    float o = 0.f;
    #pragma unroll
    for (int u=0; u<16; ++u) o += ag1[s][u*3+i]*ldfr(Wo1, u*16+w, F32);
    x1s[s][t] = ldfr(nf, n*80+32+t, F32) + o*0.25f;
  }
  __syncthreads();
  {
    float f0 = 0.f;
    #pragma unroll
    for (int u=0; u<32; ++u) f0 += x0s[s][u]*ldfr(Wf10, u*64+t, F32);
    a0s[s][t] = siluf(f0*0.17677669529663687f);
  }
  if (t < 48){
    int w = t/3, i = t - w*3;
    float f1 = 0.f;
    #pragma unroll
    for (int u=0; u<16; ++u) f1 += x1s[s][u*3+i]*ldfr(Wf11, u*16+w, F32);
    f1s[s][t] = f1*0.25f;
  }
  __syncthreads();
  if (t < 16){
    float a = f1s[s][t*3], b = f1s[s][t*3+1], c = f1s[s][t*3+2];
    float nrm = sqrtf(a*a+b*b+c*c);
    float safe = fmaxf(nrm, 1e-8f);
    coefs[s][t] = (nrm < 1e-8f) ? 0.f : siluf(nrm)/safe;
  }
  __syncthreads();
  if (t < 32){
    float g = 0.f;
    #pragma unroll
    for (int u=0; u<64; ++u) g += a0s[s][u]*ldfr(Wf20, u*32+t, F32);
    float val = x0s[s][t] + g*0.125f;
    if (F32) ((float*)out)[n*80+t] = val; else ((ushort*)out)[n*80+t] = f2b(val);
  }
  if (t < 48){
    int w = t/3, i = t - w*3;
    float g = 0.f;
    #pragma unroll
    for (int u=0; u<16; ++u) g += coefs[s][u]*f1s[s][u*3+i]*ldfr(Wf21, u*16+w, F32);
    float val = x1s[s][t] + g*0.25f;
    if (F32) ((float*)out)[n*80+32+t] = val; else ((ushort*)out)[n*80+32+t] = f2b(val);
  }
}

extern "C" void kernel_launch(void* const* d_in, const int* in_sizes, int n_in,
                              void* d_out, int out_size, void* d_ws, size_t ws_size,
                              hipStream_t stream){
  const void* nf   = d_in[0];
  const int*  eidx = (const int*)d_in[1];
  const void* esh  = d_in[2];
  const void* emb  = d_in[3];
  const void* Wq0  = d_in[4];
  const void* Wq1  = d_in[5];
  const void* Wk1  = d_in[6];
  const void* bk1  = d_in[7];
  const void* Wk2  = d_in[8];
  const void* bk2  = d_in[9];
  const void* Wv1  = d_in[10];
  const void* bv1  = d_in[11];
  const void* Wv2  = d_in[12];
  const void* bv2  = d_in[13];
  const void* Wd0  = d_in[14];
  const void* Wd1  = d_in[15];
  const void* Wo0  = d_in[16];
  const void* Wo1  = d_in[17];
  const void* Wf10 = d_in[18];
  const void* Wf11 = d_in[19];
  const void* Wf20 = d_in[20];
  const void* Wf21 = d_in[21];
  float* ws = (float*)d_ws;

  float* agg0  = ws + OFF_AGG0;
  float* agg1  = ws + OFF_AGG1;
  float* denom = ws + OFF_DEN;
  int*   flag  = (int*)(ws + OFF_FLAG);
  ushort* W2T  = (ushort*)(ws + OFF_W2T);
  float* qt0   = ws + OFF_QT0;
  float* qt1   = ws + OFF_QT1;
  float* W1T   = ws + OFF_W1T;
  uint*  W1P   = (uint*)(ws + OFF_W1P);

  prep_kernel<<<121, 256, 0, stream>>>(nf, Wk2, Wv2, Wk1, Wv1, Wq0, Wq1, Wd0, Wd1,
                                       W2T, W1T, W1P, qt0, qt1, agg0, flag);
  edge_kernel<<<N_EDGES/64, 512, 0, stream>>>(nf, eidx, esh, emb,
                                              W1T, W1P, bk1, bk2, bv1, bv2,
                                              W2T, qt0, qt1,
                                              agg0, agg1, denom, flag);
  node_out_kernel<<<N_NODES/4, 256, 0, stream>>>(nf, agg0, agg1, denom,
                                                 Wo0, Wo1, Wf10, Wf11, Wf20, Wf21, d_out, flag);
}

// Round 8
// 202.672 us; speedup vs baseline: 1.1405x; 1.1405x over previous
//
#include <hip/hip_runtime.h>

typedef unsigned int uint;
typedef unsigned short ushort;
typedef __attribute__((ext_vector_type(8))) short bf16x8;
typedef __attribute__((ext_vector_type(4))) float f32x4;
typedef __attribute__((ext_vector_type(2))) float f32x2;

#define N_NODES 2000
#define N_EDGES 32000
#define WNUM 2304

// ---------- ws layout (float element offsets) ----------
constexpr size_t OFF_AGG0 = 0;        // 2000*32
constexpr size_t OFF_AGG1 = 64000;    // 2000*48
constexpr size_t OFF_DEN  = 160000;   // 2000*4  (zero-fill covers 0..168000)
constexpr size_t OFF_FLAG = 170000;   // 1 int
constexpr size_t OFF_W2T  = 170004;   // ushort[2][2304][64] = 147456 floats
constexpr size_t OFF_QT0  = 317460;   // 2000*32
constexpr size_t OFF_QT1  = 381460;   // 2000*48
constexpr size_t OFF_W1T  = 509460;   // float[2][64][16] = 2048 floats
constexpr size_t OFF_W1P  = 511508;   // uint[2][64][8]   = 1024 uints (packed bf16 pairs)

__device__ __forceinline__ float b2f(ushort u){ union{uint i; float f;}x; x.i=((uint)u)<<16; return x.f; }
__device__ __forceinline__ float lo16(uint w){ union{uint u; float f;}x; x.u=w<<16; return x.f; }
__device__ __forceinline__ float hi16(uint w){ union{uint u; float f;}x; x.u=w&0xFFFF0000u; return x.f; }
__device__ __forceinline__ ushort f2b(float f){
  union{float f; uint u;}x; x.f=f;
  uint r = (x.u + 0x7FFFu + ((x.u>>16)&1u)) >> 16;
  return (ushort)r;
}
__device__ __forceinline__ float siluf(float x){ return x / (1.f + __expf(-x)); }

template<bool F32>
__device__ __forceinline__ float ldf(const void* p, int i){
  if (F32) return ((const float*)p)[i];
  return b2f(((const ushort*)p)[i]);
}
__device__ __forceinline__ float ldfr(const void* p, int i, bool f32){
  return f32 ? ((const float*)p)[i] : b2f(((const ushort*)p)[i]);
}

// ---------- K0 body: W2 transpose + W1 transpose/pack + node_q + agg zero-fill ----------
template<bool F32>
__device__ void prep_body(
    const void* __restrict__ nf,
    const void* __restrict__ Wk2, const void* __restrict__ Wv2,
    const void* __restrict__ Wk1, const void* __restrict__ Wv1,
    const void* __restrict__ Wq0, const void* __restrict__ Wq1,
    const void* __restrict__ Wd0, const void* __restrict__ Wd1,
    ushort* __restrict__ W2T, float* __restrict__ W1T, uint* __restrict__ W1P,
    float* __restrict__ qt0, float* __restrict__ qt1,
    float* __restrict__ aggz){
  const int t = threadIdx.x;
  const int bid = blockIdx.x;

  if (bid < 72){
    __shared__ ushort tile[64][66];
    const int mat = bid / 36, jt = bid - mat*36;
    const void* W = mat ? Wv2 : Wk2;
    const int j0 = jt*64;
    const int jo = t & 63, cb = t >> 6;
    #pragma unroll
    for (int k=0; k<16; ++k){
      const int c = cb + k*4;
      tile[c][jo] = F32 ? f2b(((const float*)W)[(size_t)c*WNUM + j0 + jo])
                        : ((const ushort*)W)[(size_t)c*WNUM + j0 + jo];
    }
    __syncthreads();
    const int jl = t >> 2, c0 = (t & 3)*16;
    ushort* dst = W2T + (size_t)mat*147456 + (size_t)(j0+jl)*64 + c0;
    #pragma unroll
    for (int k=0; k<16; ++k) dst[k] = tile[c0+k][jl];
  } else if (bid < 104){
    __shared__ float nfL[64][80];
    __shared__ float wq0L[1024], wq1L[256], wd0L[64], wd1L[16];
    const int nb = bid - 72, n0 = nb*64;
    // vectorized staging: nfL region is 64 CONSECUTIVE nf rows (5120 elems linear)
    if (F32){
      for (int idx=t; idx<1280; idx+=256){
        const int gi = n0*20 + idx;            // float4 index, bound 2000*20
        float4 v;
        if (gi < 40000) v = ((const float4*)nf)[gi];
        else { v.x=0.f; v.y=0.f; v.z=0.f; v.w=0.f; }
        ((float4*)&nfL[0][0])[idx] = v;
      }
    } else {
      for (int idx=t; idx<640; idx+=256){
        const int gi = n0*10 + idx;            // uint4(=8 bf16) index, bound 2000*10
        uint4 v;
        if (gi < 20000) v = ((const uint4*)nf)[gi];
        else { v.x=0u; v.y=0u; v.z=0u; v.w=0u; }
        float* d = &nfL[0][0] + idx*8;
        d[0]=lo16(v.x); d[1]=hi16(v.x); d[2]=lo16(v.y); d[3]=hi16(v.y);
        d[4]=lo16(v.z); d[5]=hi16(v.z); d[6]=lo16(v.w); d[7]=hi16(v.w);
      }
    }
    for (int idx=t; idx<1024; idx+=256) wq0L[idx] = ldf<F32>(Wq0, idx);
    if (t < 256) wq1L[t] = ldf<F32>(Wq1, t);
    if (t < 64)  wd0L[t] = ldf<F32>(Wd0, t);
    if (t < 16)  wd1L[t] = ldf<F32>(Wd1, t);
    __syncthreads();
    const int nl = t >> 2, h = t & 3;
    const int nn = n0 + nl;
    if (nn < N_NODES){
      const float* S = &nfL[nl][0];
      float q0[8];
      #pragma unroll
      for (int w=0; w<8; ++w){
        float a = 0.f;
        #pragma unroll
        for (int u=0; u<32; ++u) a += S[u]*wq0L[h*256 + u*8 + w];
        q0[w] = a * 0.17677669529663687f;   // 1/sqrt(32)
      }
      #pragma unroll
      for (int vv=0; vv<8; ++vv){
        float a = 0.f;
        #pragma unroll
        for (int u=0; u<8; ++u) a += q0[u]*wd0L[u*8+vv];
        qt0[nn*32 + h*8 + vv] = a;
      }
      float q1[12];
      #pragma unroll
      for (int w=0; w<4; ++w)
        #pragma unroll
        for (int i=0; i<3; ++i){
          float a = 0.f;
          #pragma unroll
          for (int u=0; u<16; ++u) a += S[32+u*3+i]*wq1L[h*64 + u*4 + w];
          q1[w*3+i] = a * 0.25f;            // 1/sqrt(16)
        }
      #pragma unroll
      for (int vv=0; vv<4; ++vv)
        #pragma unroll
        for (int i=0; i<3; ++i){
          float a = 0.f;
          #pragma unroll
          for (int u=0; u<4; ++u) a += q1[u*3+i]*wd1L[u*4+vv];
          qt1[nn*48 + h*12 + vv*3 + i] = a;
        }
    }
  } else if (bid == 104){
    // W1 transpose (f32) + packed bf16
    for (int idx=t; idx<2048; idx+=256){
      const int mat = idx >> 10, rem = idx & 1023;
      const int c = rem >> 4, b = rem & 15;
      W1T[idx] = ldf<F32>(mat ? Wv1 : Wk1, b*64 + c);
    }
    for (int idx=t; idx<1024; idx+=256){
      const int mat = idx >> 9, rem = idx & 511;
      const int c = rem >> 3, j = rem & 7;
      const void* W = mat ? Wv1 : Wk1;
      ushort u0, u1;
      if (F32){ u0 = f2b(((const float*)W)[(2*j)*64+c]); u1 = f2b(((const float*)W)[(2*j+1)*64+c]); }
      else    { u0 = ((const ushort*)W)[(2*j)*64+c];     u1 = ((const ushort*)W)[(2*j+1)*64+c]; }
      W1P[idx] = (uint)u0 | ((uint)u1 << 16);
    }
  } else {
    // bid 105..120: zero agg0/agg1/denom (168000 floats = 42000 float4), replaces memset launch
    float4 z; z.x=0.f; z.y=0.f; z.z=0.f; z.w=0.f;
    for (int i = (bid-105)*256 + t; i < 42000; i += 4096)
      ((float4*)aggz)[i] = z;
  }
}

__global__ __launch_bounds__(256) void prep_kernel(
    const void* nf,
    const void* Wk2, const void* Wv2,
    const void* Wk1, const void* Wv1,
    const void* Wq0, const void* Wq1,
    const void* Wd0, const void* Wd1,
    ushort* W2T, float* W1T, uint* W1P, float* qt0, float* qt1,
    float* aggz, int* flag){
  __shared__ int s_cnt;
  const int t = threadIdx.x;
  if (t == 0) s_cnt = 0;
  __syncthreads();
  {
    uint u = ((const ushort*)nf)[t*2];
    uint ex = (u >> 7) & 0xFFu;
    if (ex >= 0xA0u) atomicAdd(&s_cnt, 1);
  }
  __syncthreads();
  const bool F32 = (s_cnt >= 20);
  if (blockIdx.x == 0 && t == 0) *flag = F32 ? 1 : 0;
  if (F32) prep_body<true >(nf, Wk2, Wv2, Wk1, Wv1, Wq0, Wq1, Wd0, Wd1, W2T, W1T, W1P, qt0, qt1, aggz);
  else     prep_body<false>(nf, Wk2, Wv2, Wk1, Wv1, Wq0, Wq1, Wd0, Wd1, W2T, W1T, W1P, qt0, qt1, aggz);
}

// ---------- K3: fused edge kernel ----------
// 64 edges/block, 512 threads = 8 waves = (kv:2) x (h:4). Each wave: 36 tiles x 4 Mt.
// Capacity: LDS 77.2KB -> 2 blocks/CU; VGPR must stay <= 128 (4 waves/SIMD) for
// single-residency (500 <= 512).
// NOTE 1: plain __launch_bounds__(512) — adding the 2nd arg makes hipcc collapse to
//         64 VGPR and spill (rounds 1 & 5: 67-91 MB scratch traffic).
// NOTE 2: tile loops at unroll 2 with 2-deep ping-pong prefetch — unroll 4 / full
//         unroll overflows the 128-VGPR tier and spills (round 7: 93 MB scratch).
// a0/aP accumulators are parked to LDS after their tile phases to keep peak VGPR down.
struct Smem {
  ushort hidA[8192];            // [kv][Mt(4)][kh][lane*8] = 16384 B
  union {
    struct {
      float fssT[32][66];       // rows 0..31 (ss*sh0)
      float fvvT[16][66];       // rows 32..47 (seamless continuation)
      float sslT[32][66];
    } f;                        // 21120 B
    float cont[5376];           // [el][h][comp] 64*4*21 (live only after barrier #2)
  } u;                          // 21504 B
  float vshT[3][16][66];        // 12672 B
  float sh1T[3][66];            // 792 B
  float park0[2][4][64][8];     // 16384 B  a0 parked:  [kv][h][el][w<8]
  float parkP[2][4][64][4];     // 8192 B   aP parked:  [kv][h][el][w<4]
  float exL[64][4];             // 1024 B   K->V exp(logit) handoff
  int   dstL[64];               // 256 B
};                              // 77,208 B -> 2 blocks/CU (154 KB <= 160)

__device__ __forceinline__ f32x4 mma_pair(const bf16x8& a0f, const bf16x8& a1f,
                                          bf16x8 b0, bf16x8 b1, float bb){
  f32x4 c = {bb,bb,bb,bb};
  c = __builtin_amdgcn_mfma_f32_16x16x32_bf16(a0f, b0, c, 0,0,0);
  c = __builtin_amdgcn_mfma_f32_16x16x32_bf16(a1f, b1, c, 0,0,0);
  return c;
}
__device__ __forceinline__ void acc_feat(const f32x4 c, const float* fp, float* acc){
  f32x2 fA = *(const f32x2*)(fp);
  f32x2 fB = *(const f32x2*)(fp + 2);
  acc[0] += c[0]*fA[0]; acc[1] += c[1]*fA[1];
  acc[2] += c[2]*fB[0]; acc[3] += c[3]*fB[1];
}

template<bool F32>
__device__ void edge_body(
    const void* __restrict__ nf,  const int* __restrict__ eidx,
    const void* __restrict__ esh, const void* __restrict__ emb,
    const float* __restrict__ W1T, const uint* __restrict__ W1P,
    const void* __restrict__ bk1, const void* __restrict__ bk2,
    const void* __restrict__ bv1, const void* __restrict__ bv2,
    const ushort* __restrict__ W2T,
    const float* __restrict__ qt0g, const float* __restrict__ qt1g,
    float* __restrict__ agg0, float* __restrict__ agg1, float* __restrict__ denom,
    Smem& sm){
  const int t  = threadIdx.x;
  const int geb = blockIdx.x*64;

  // ---- Phase A: 16 groups x 4 edges, batched gathers (sequential edge ids) ----
  {
    const int g = t >> 5, r = t & 31;
    int geA[4], srcA[4], dstA[4];
    float shv0[4], shv1[4], shv2[4], shv3[4];
    #pragma unroll
    for (int e=0; e<4; ++e) geA[e] = geb + g*4 + e;
    #pragma unroll
    for (int e=0; e<4; ++e){ srcA[e] = eidx[geA[e]]; dstA[e] = eidx[N_EDGES + geA[e]]; }
    #pragma unroll
    for (int e=0; e<4; ++e){
      if (F32){
        float4 s4 = ((const float4*)esh)[geA[e]];
        shv0[e]=s4.x; shv1[e]=s4.y; shv2[e]=s4.z; shv3[e]=s4.w;
      } else {
        uint2 u2 = ((const uint2*)esh)[geA[e]];
        shv0[e]=lo16(u2.x); shv1[e]=hi16(u2.x); shv2[e]=lo16(u2.y); shv3[e]=hi16(u2.y);
      }
    }
    #pragma unroll
    for (int e=0; e<4; ++e){
      const int le = g*4+e, src = srcA[e];
      const float sh0 = shv0[e], s1a = shv1[e], s1b = shv2[e], s1c = shv3[e];
      if (r == 0) sm.dstL[le] = dstA[e];
      if (r < 3) sm.sh1T[r][le] = (r==0)? s1a : (r==1)? s1b : s1c;
      float sv = ldf<F32>(nf, src*80 + r);
      sm.u.f.sslT[r][le] = sv;
      sm.u.f.fssT[r][le] = sv * sh0;
      if (r < 16){
        float v0 = ldf<F32>(nf, src*80+32+r*3+0);
        float v1 = ldf<F32>(nf, src*80+32+r*3+1);
        float v2 = ldf<F32>(nf, src*80+32+r*3+2);
        sm.vshT[0][r][le] = v0*sh0; sm.vshT[1][r][le] = v1*sh0; sm.vshT[2][r][le] = v2*sh0;
        sm.u.f.fvvT[r][le] = (v0*s1a + v1*s1b + v2*s1c) * 0.5773502691896258f;
      }
    }
  }

  // ---- Phase B: radial MLP hidden; 1 column x 8 edges per thread ----
  {
    const int c  = t & 63;
    const int g8 = t >> 6;
    const int le0 = g8*8;
    float bkv = ldf<F32>(bk1, c), bvv = ldf<F32>(bv1, c);
    f32x4 wkF[4], wvF[4];       // F32 instantiation only
    uint4 wkB[2], wvB[2];       // bf16 instantiation only
    if (F32){
      const f32x4* pk = (const f32x4*)(W1T + c*16);
      const f32x4* pv = (const f32x4*)(W1T + 1024 + c*16);
      wkF[0]=pk[0]; wkF[1]=pk[1]; wkF[2]=pk[2]; wkF[3]=pk[3];
      wvF[0]=pv[0]; wvF[1]=pv[1]; wvF[2]=pv[2]; wvF[3]=pv[3];
    } else {
      const uint4* pk = (const uint4*)(W1P + c*8);
      const uint4* pv = (const uint4*)(W1P + 512 + c*8);
      wkB[0]=pk[0]; wkB[1]=pk[1];
      wvB[0]=pv[0]; wvB[1]=pv[1];
    }
    uint4 ra, rb; float4 fa, fb, fc, fd;
    if (F32){
      const float4* p = (const float4*)emb + (size_t)(geb+le0)*4;
      fa = p[0]; fb = p[1]; fc = p[2]; fd = p[3];
    } else {
      const uint4* p = (const uint4*)emb + (size_t)(geb+le0)*2;
      ra = p[0]; rb = p[1];
    }
    #pragma unroll
    for (int e=0; e<8; ++e){
      float em[16];
      if (F32){
        em[0]=fa.x; em[1]=fa.y; em[2]=fa.z; em[3]=fa.w;
        em[4]=fb.x; em[5]=fb.y; em[6]=fb.z; em[7]=fb.w;
        em[8]=fc.x; em[9]=fc.y; em[10]=fc.z; em[11]=fc.w;
        em[12]=fd.x; em[13]=fd.y; em[14]=fd.z; em[15]=fd.w;
      } else {
        em[0]=lo16(ra.x); em[1]=hi16(ra.x); em[2]=lo16(ra.y); em[3]=hi16(ra.y);
        em[4]=lo16(ra.z); em[5]=hi16(ra.z); em[6]=lo16(ra.w); em[7]=hi16(ra.w);
        em[8]=lo16(rb.x); em[9]=hi16(rb.x); em[10]=lo16(rb.y); em[11]=hi16(rb.y);
        em[12]=lo16(rb.z); em[13]=hi16(rb.z); em[14]=lo16(rb.w); em[15]=hi16(rb.w);
      }
      if (e < 7){
        if (F32){
          const float4* p = (const float4*)emb + (size_t)(geb+le0+e+1)*4;
          fa = p[0]; fb = p[1]; fc = p[2]; fd = p[3];
        } else {
          const uint4* p = (const uint4*)emb + (size_t)(geb+le0+e+1)*2;
          ra = p[0]; rb = p[1];
        }
      }
      const int le = le0+e;
      float ak = bkv, av = bvv;
      if (F32){
        #pragma unroll
        for (int g=0; g<4; ++g)
          #pragma unroll
          for (int j=0; j<4; ++j){
            ak += em[g*4+j]*wkF[g][j];
            av += em[g*4+j]*wvF[g][j];
          }
      } else {
        #pragma unroll
        for (int g=0; g<2; ++g){
          const uint4 a = wkB[g], b = wvB[g];
          ak += em[g*8+0]*lo16(a.x) + em[g*8+1]*hi16(a.x)
              + em[g*8+2]*lo16(a.y) + em[g*8+3]*hi16(a.y)
              + em[g*8+4]*lo16(a.z) + em[g*8+5]*hi16(a.z)
              + em[g*8+6]*lo16(a.w) + em[g*8+7]*hi16(a.w);
          av += em[g*8+0]*lo16(b.x) + em[g*8+1]*hi16(b.x)
              + em[g*8+2]*lo16(b.y) + em[g*8+3]*hi16(b.y)
              + em[g*8+4]*lo16(b.z) + em[g*8+5]*hi16(b.z)
              + em[g*8+6]*lo16(b.w) + em[g*8+7]*hi16(b.w);
        }
      }
      // fragment-linear hidA index: Mt*1024 + kh*512 + (q*16+m)*8 + j   (kv offset 0/4096)
      const int idx = (le>>4)*1024 + (c>>5)*512 + ((((c>>3)&3)*16 + (le&15))<<3) + (c&7);
      sm.hidA[idx]        = f2b(siluf(ak));
      sm.hidA[4096 + idx] = f2b(siluf(av));
    }
  }
  __syncthreads();   // barrier #1: hidA + features ready

  // ---- Phase C: one 36-tile pass per wave; wave = (kv, h); 4 Mt per step ----
  const int w  = t >> 6;
  const int kv = w >> 2;
  const int h  = w & 3;
  const int lane = t & 63, q = lane >> 4, n = lane & 15;
  const float invfan = 0.14433756729740643f;   // 1/sqrt(48)

  const ushort* wptr = W2T + (size_t)kv*147456 + h*36864 + n*64 + q*8;  // tile stride 1024
  const void* bvec = kv ? bv2 : bk2;
  const int bi0 = h*576 + n;                        // bias idx, tile stride 16
  const float* fb_ss = &sm.u.f.fssT[n>>3][q*4];     // + tl*132 + Mt*16 (rows 0..47 seamless)
  const float* fb_sl = &sm.u.f.sslT[n>>2][q*4];     // + (tl-24)*264 + Mt*16
  const int nq2 = n>>2;

  bf16x8 af[4][2];
  #pragma unroll
  for (int Mt=0; Mt<4; ++Mt)
    #pragma unroll
    for (int kh=0; kh<2; ++kh)
      af[Mt][kh] = *(const bf16x8*)&sm.hidA[kv*4096 + Mt*1024 + kh*512 + lane*8];

#define PREF(P0,P1,PB,TL) \
  P0 = *(const bf16x8*)(wptr + (TL)*1024); \
  P1 = *(const bf16x8*)(wptr + (TL)*1024 + 32); \
  PB = ldf<F32>(bvec, bi0 + (TL)*16);

  // 2-deep ping-pong prefetch
  bf16x8 pA0, pA1, pB0, pB1; float pAb, pBb;
  PREF(pA0, pA1, pAb, 0);
  PREF(pB0, pB1, pBb, 1);

  // ss tiles 0..15 + vv tiles 16..23 -> a0
  {
    float a0[4][4];
    #pragma unroll
    for (int Mt=0; Mt<4; ++Mt){ a0[Mt][0]=0.f; a0[Mt][1]=0.f; a0[Mt][2]=0.f; a0[Mt][3]=0.f; }
    #pragma unroll 2
    for (int tl=0; tl<24; tl+=2){
      { bf16x8 b0=pA0, b1=pA1; float bb=pAb;
        PREF(pA0, pA1, pAb, tl+2);
        const float* fp = fb_ss + tl*132;
        #pragma unroll
        for (int Mt=0; Mt<4; ++Mt) acc_feat(mma_pair(af[Mt][0], af[Mt][1], b0, b1, bb), fp + Mt*16, a0[Mt]); }
      { bf16x8 b0=pB0, b1=pB1; float bb=pBb;
        PREF(pB0, pB1, pBb, tl+3);
        const float* fp = fb_ss + (tl+1)*132;
        #pragma unroll
        for (int Mt=0; Mt<4; ++Mt) acc_feat(mma_pair(af[Mt][0], af[Mt][1], b0, b1, bb), fp + Mt*16, a0[Mt]); }
    }
    // reduce + park a0 (freed before aP phase)
    #pragma unroll
    for (int Mt=0; Mt<4; ++Mt)
      #pragma unroll
      for (int z=0; z<4; ++z){
        a0[Mt][z] += __shfl_xor(a0[Mt][z], 8, 64);
        if (n < 8) sm.park0[kv][h][Mt*16 + q*4 + z][n] = a0[Mt][z];
      }
  }

  // sv tiles 24..31 -> aP
  {
    float aP[4][4];
    #pragma unroll
    for (int Mt=0; Mt<4; ++Mt){ aP[Mt][0]=0.f; aP[Mt][1]=0.f; aP[Mt][2]=0.f; aP[Mt][3]=0.f; }
    #pragma unroll 2
    for (int tl=24; tl<32; tl+=2){
      { bf16x8 b0=pA0, b1=pA1; float bb=pAb;
        PREF(pA0, pA1, pAb, tl+2);
        const float* fp = fb_sl + (tl-24)*264;
        #pragma unroll
        for (int Mt=0; Mt<4; ++Mt) acc_feat(mma_pair(af[Mt][0], af[Mt][1], b0, b1, bb), fp + Mt*16, aP[Mt]); }
      { bf16x8 b0=pB0, b1=pB1; float bb=pBb;
        PREF(pB0, pB1, pBb, tl+3);
        const float* fp = fb_sl + (tl-23)*264;
        #pragma unroll
        for (int Mt=0; Mt<4; ++Mt) acc_feat(mma_pair(af[Mt][0], af[Mt][1], b0, b1, bb), fp + Mt*16, aP[Mt]); }
    }
    // reduce + park aP
    #pragma unroll
    for (int Mt=0; Mt<4; ++Mt)
      #pragma unroll
      for (int z=0; z<4; ++z){
        aP[Mt][z] += __shfl_xor(aP[Mt][z], 4, 64);
        aP[Mt][z] += __shfl_xor(aP[Mt][z], 8, 64);
        if (n < 4) sm.parkP[kv][h][Mt*16 + q*4 + z][n] = aP[Mt][z];
      }
  }

  // vs tiles 32..35 -> aW[i] (kept in registers)
  float aW[3][4][4];
  #pragma unroll
  for (int i=0; i<3; ++i)
    #pragma unroll
    for (int Mt=0; Mt<4; ++Mt){ aW[i][Mt][0]=0.f; aW[i][Mt][1]=0.f; aW[i][Mt][2]=0.f; aW[i][Mt][3]=0.f; }
#define BODY_AW(B0,B1,BB,TL) { \
    const int u = ((TL)-32)*4 + nq2; \
    _Pragma("unroll") \
    for (int Mt=0; Mt<4; ++Mt){ \
      f32x4 c = mma_pair(af[Mt][0], af[Mt][1], B0, B1, BB); \
      _Pragma("unroll") \
      for (int i=0; i<3; ++i) acc_feat(c, &sm.vshT[i][u][Mt*16+q*4], aW[i][Mt]); \
    } }
  { bf16x8 b0=pA0, b1=pA1; float bb=pAb; PREF(pA0, pA1, pAb, 34); BODY_AW(b0,b1,bb,32); }
  { bf16x8 b0=pB0, b1=pB1; float bb=pBb; PREF(pB0, pB1, pBb, 35); BODY_AW(b0,b1,bb,33); }
  { bf16x8 b0=pA0, b1=pA1; float bb=pAb; BODY_AW(b0,b1,bb,34); }
  { bf16x8 b0=pB0, b1=pB1; float bb=pBb; BODY_AW(b0,b1,bb,35); }
#undef BODY_AW
#undef PREF
  #pragma unroll
  for (int i=0; i<3; ++i)
    #pragma unroll
    for (int Mt=0; Mt<4; ++Mt)
      #pragma unroll
      for (int z=0; z<4; ++z){
        aW[i][Mt][z] += __shfl_xor(aW[i][Mt][z], 4, 64);
        aW[i][Mt][z] += __shfl_xor(aW[i][Mt][z], 8, 64);
      }

  if (kv == 0){
    // K-waves: logits -> exp -> exL handoff
    float lgp[4][4];
    #pragma unroll
    for (int Mt=0; Mt<4; ++Mt)
      #pragma unroll
      for (int z=0; z<4; ++z){
        const int el = Mt*16 + q*4 + z;
        const int d = sm.dstL[el];
        float acc = 0.f;
        if (n < 8) acc = qt0g[d*32 + h*8 + n] * sm.park0[0][h][el][n];
        if (n < 4){
          const float aPv = sm.parkP[0][h][el][n];
          float s = 0.f;
          #pragma unroll
          for (int i=0; i<3; ++i){
            float k1 = aPv*sm.sh1T[i][el] + aW[i][Mt][z];
            s += qt1g[d*48 + h*12 + n*3 + i] * k1;
          }
          acc += s * 0.5773502691896258f;
        }
        lgp[Mt][z] = acc;
      }
    #pragma unroll
    for (int Mt=0; Mt<4; ++Mt)
      #pragma unroll
      for (int z=0; z<4; ++z){
        lgp[Mt][z] += __shfl_xor(lgp[Mt][z], 1, 64);
        lgp[Mt][z] += __shfl_xor(lgp[Mt][z], 2, 64);
        lgp[Mt][z] += __shfl_xor(lgp[Mt][z], 4, 64);
        lgp[Mt][z] += __shfl_xor(lgp[Mt][z], 8, 64);
      }
    if (n == 0){
      #pragma unroll
      for (int Mt=0; Mt<4; ++Mt)
        #pragma unroll
        for (int z=0; z<4; ++z){
          float lg = lgp[Mt][z] * invfan * 0.025f;   // 1/(sqrt(80)*sqrt(20))
          lg = fminf(10.f, fmaxf(-10.f, lg));
          sm.exL[Mt*16 + q*4 + z][h] = __expf(lg - 10.0f);  // fixed softmax max = 10
        }
    }
  }
  __syncthreads();   // barrier #2: exL ready; all tile-loop feature reads done

  if (kv == 1){
    // V-waves: stage cont (overlays feature arrays — protected by barrier #2)
    #pragma unroll
    for (int Mt=0; Mt<4; ++Mt)
      #pragma unroll
      for (int z=0; z<4; ++z){
        const int el = Mt*16 + q*4 + z;
        const float ex = sm.exL[el][h];
        float* cp = &sm.u.cont[el*84 + h*21];
        if (n == 0) cp[0] = ex;
        if (n < 8)  cp[1+n] = ex * sm.park0[1][h][el][n] * invfan;
        if (n < 4){
          const float aPv = sm.parkP[1][h][el][n];
          #pragma unroll
          for (int i=0; i<3; ++i){
            float v1 = (aPv*sm.sh1T[i][el] + aW[i][Mt][z]) * invfan;
            cp[9+n*3+i] = ex * v1;
          }
        }
      }
  }
  __syncthreads();   // barrier #3: cont ready

  // flat atomic scatter: 5376 values, stride-1 LDS reads (conflict-free)
  #pragma unroll
  for (int k=0; k<11; ++k){
    const int idx = t + k*512;
    if (idx < 5376){
      const int el = idx / 84;
      const int cm = idx - el*84;
      const int h2 = cm / 21;
      const int comp = cm - h2*21;
      const float val = sm.u.cont[idx];
      const int d2 = sm.dstL[el];
      if (comp == 0)      atomicAdd(denom + d2*4  + h2, val);
      else if (comp < 9)  atomicAdd(agg0  + d2*32 + h2*8  + (comp-1), val);
      else                atomicAdd(agg1  + d2*48 + h2*12 + (comp-9), val);
    }
  }
}

__global__ __launch_bounds__(512) void edge_kernel(
    const void* nf, const int* eidx, const void* esh, const void* emb,
    const float* W1T, const uint* W1P,
    const void* bk1, const void* bk2,
    const void* bv1, const void* bv2,
    const ushort* W2T, const float* qt0g, const float* qt1g,
    float* agg0, float* agg1, float* denom, const int* flag){
  __shared__ Smem sm;
  if (*flag)
    edge_body<true >(nf,eidx,esh,emb,W1T,W1P,bk1,bk2,bv1,bv2,W2T,qt0g,qt1g,agg0,agg1,denom,sm);
  else
    edge_body<false>(nf,eidx,esh,emb,W1T,W1P,bk1,bk2,bv1,bv2,W2T,qt0g,qt1g,agg0,agg1,denom,sm);
}

// ---------- K4: per-node output MLP (4 nodes per 256-thread block) ----------
__global__ __launch_bounds__(256) void node_out_kernel(
    const void* __restrict__ nf, const float* __restrict__ agg0r, const float* __restrict__ agg1r,
    const float* __restrict__ denom,
    const void* __restrict__ Wo0, const void* __restrict__ Wo1,
    const void* __restrict__ Wf10, const void* __restrict__ Wf11,
    const void* __restrict__ Wf20, const void* __restrict__ Wf21,
    void* __restrict__ out, const int* __restrict__ flag){
  __shared__ float ag0[4][32], ag1[4][48], adiv[4][4];
  __shared__ float x0s[4][32], x1s[4][48], a0s[4][64], f1s[4][48], coefs[4][16];
  const bool F32 = (*flag) != 0;
  const int s = threadIdx.x >> 6, t = threadIdx.x & 63;
  const int n = blockIdx.x*4 + s;
  if (t < 4) adiv[s][t] = 1.f / (denom[n*4+t] + 1e-12f);
  __syncthreads();
  if (t < 32) ag0[s][t] = agg0r[n*32+t] * adiv[s][t>>3];
  if (t < 48) ag1[s][t] = agg1r[n*48+t] * adiv[s][t/12];
  __syncthreads();
  if (t < 32){
    float o = 0.f;
    #pragma unroll
    for (int k=0; k<32; ++k) o += ag0[s][k]*ldfr(Wo0, k*32+t, F32);
    x0s[s][t] = ldfr(nf, n*80+t, F32) + o*0.17677669529663687f;
  }
  if (t < 48){
    int w = t/3, i = t - w*3;
    float o = 0.f;
    #pragma unroll
    for (int u=0; u<16; ++u) o += ag1[s][u*3+i]*ldfr(Wo1, u*16+w, F32);
    x1s[s][t] = ldfr(nf, n*80+32+t, F32) + o*0.25f;
  }
  __syncthreads();
  {
    float f0 = 0.f;
    #pragma unroll
    for (int u=0; u<32; ++u) f0 += x0s[s][u]*ldfr(Wf10, u*64+t, F32);
    a0s[s][t] = siluf(f0*0.17677669529663687f);
  }
  if (t < 48){
    int w = t/3, i = t - w*3;
    float f1 = 0.f;
    #pragma unroll
    for (int u=0; u<16; ++u) f1 += x1s[s][u*3+i]*ldfr(Wf11, u*16+w, F32);
    f1s[s][t] = f1*0.25f;
  }
  __syncthreads();
  if (t < 16){
    float a = f1s[s][t*3], b = f1s[s][t*3+1], c = f1s[s][t*3+2];
    float nrm = sqrtf(a*a+b*b+c*c);
    float safe = fmaxf(nrm, 1e-8f);
    coefs[s][t] = (nrm < 1e-8f) ? 0.f : siluf(nrm)/safe;
  }
  __syncthreads();
  if (t < 32){
    float g = 0.f;
    #pragma unroll
    for (int u=0; u<64; ++u) g += a0s[s][u]*ldfr(Wf20, u*32+t, F32);
    float val = x0s[s][t] + g*0.125f;
    if (F32) ((float*)out)[n*80+t] = val; else ((ushort*)out)[n*80+t] = f2b(val);
  }
  if (t < 48){
    int w = t/3, i = t - w*3;
    float g = 0.f;
    #pragma unroll
    for (int u=0; u<16; ++u) g += coefs[s][u]*f1s[s][u*3+i]*ldfr(Wf21, u*16+w, F32);
    float val = x1s[s][t] + g*0.25f;
    if (F32) ((float*)out)[n*80+32+t] = val; else ((ushort*)out)[n*80+32+t] = f2b(val);
  }
}

extern "C" void kernel_launch(void* const* d_in, const int* in_sizes, int n_in,
                              void* d_out, int out_size, void* d_ws, size_t ws_size,
                              hipStream_t stream){
  const void* nf   = d_in[0];
  const int*  eidx = (const int*)d_in[1];
  const void* esh  = d_in[2];
  const void* emb  = d_in[3];
  const void* Wq0  = d_in[4];
  const void* Wq1  = d_in[5];
  const void* Wk1  = d_in[6];
  const void* bk1  = d_in[7];
  const void* Wk2  = d_in[8];
  const void* bk2  = d_in[9];
  const void* Wv1  = d_in[10];
  const void* bv1  = d_in[11];
  const void* Wv2  = d_in[12];
  const void* bv2  = d_in[13];
  const void* Wd0  = d_in[14];
  const void* Wd1  = d_in[15];
  const void* Wo0  = d_in[16];
  const void* Wo1  = d_in[17];
  const void* Wf10 = d_in[18];
  const void* Wf11 = d_in[19];
  const void* Wf20 = d_in[20];
  const void* Wf21 = d_in[21];
  float* ws = (float*)d_ws;

  float* agg0  = ws + OFF_AGG0;
  float* agg1  = ws + OFF_AGG1;
  float* denom = ws + OFF_DEN;
  int*   flag  = (int*)(ws + OFF_FLAG);
  ushort* W2T  = (ushort*)(ws + OFF_W2T);
  float* qt0   = ws + OFF_QT0;
  float* qt1   = ws + OFF_QT1;
  float* W1T   = ws + OFF_W1T;
  uint*  W1P   = (uint*)(ws + OFF_W1P);

  prep_kernel<<<121, 256, 0, stream>>>(nf, Wk2, Wv2, Wk1, Wv1, Wq0, Wq1, Wd0, Wd1,
                                       W2T, W1T, W1P, qt0, qt1, agg0, flag);
  edge_kernel<<<N_EDGES/64, 512, 0, stream>>>(nf, eidx, esh, emb,
                                              W1T, W1P, bk1, bk2, bv1, bv2,
                                              W2T, qt0, qt1,
                                              agg0, agg1, denom, flag);
  node_out_kernel<<<N_NODES/4, 256, 0, stream>>>(nf, agg0, agg1, denom,
                                                 Wo0, Wo1, Wf10, Wf11, Wf20, Wf21, d_out, flag);
}